// Round 1
// baseline (816.917 us; speedup 1.0000x reference)
//
#include <hip/hip_runtime.h>

// Fused StyleGAN2 conv_downsample_2d:
//   out[n,oc,oh,ow] = sum_c w[c,oc] * y[n,c,2oh,2ow]
//   y = 4x4 FIR (k=[1,3,3,1] outer, /64), pad=1, on x[n,c,:,:]
//
// Shapes: x[4,128,512,512] f32, w[128,256] f32 (HWIO 1,1,128,256), out[4,256,256,256] f32.
//
// Block: 256 threads; per-block output tile = 256 oc x 8 oh x 8 ow (one batch).
// Channel loop in chunks of 8: stage x patch (18x18 per ch) + w slice in LDS,
// compute 8x8 y tile per channel, register-blocked 8oc x 8sp accumulate.

#define CH 8
#define PATCH 18
#define XPAD 20   // pad row stride to 20 floats

__global__ __launch_bounds__(256)
void fused_downconv(const float* __restrict__ x, const float* __restrict__ w,
                    float* __restrict__ out) {
    const int tid = threadIdx.x;
    const int ow0 = blockIdx.x * 8;
    const int oh0 = blockIdx.y * 8;
    const int n   = blockIdx.z;

    __shared__ float x_s[CH][PATCH][XPAD];   // 11.25 KB
    __shared__ float y_s[CH][8][8];          // 2 KB
    __shared__ float w_s[CH][256];           // 8 KB

    const int oc_g = tid >> 3;   // 0..31 -> oc block of 8
    const int sp_g = tid & 7;    // 0..7  -> output row within tile

    float acc[8][8];
    #pragma unroll
    for (int i = 0; i < 8; i++)
        #pragma unroll
        for (int j = 0; j < 8; j++) acc[i][j] = 0.f;

    const int rbase = 2 * oh0 - 1;
    const int cbase = 2 * ow0 - 1;

    // FIR coeffs: kkn = {1,3,3,1}/8 ; k2d[a][b] = kkn[a]*kkn[b] (exact dyadic)
    const float kkn[4] = {0.125f, 0.375f, 0.375f, 0.125f};

    for (int c0 = 0; c0 < 128; c0 += CH) {
        // ---- stage w slice: w_s[cc][oc] ----
        #pragma unroll
        for (int k = 0; k < CH; k++)
            w_s[k][tid] = w[(c0 + k) * 256 + tid];

        // ---- stage x patch: 8 ch x 18x18, zero-padded at borders ----
        const float* xn = x + ((size_t)(n * 128 + c0)) * 512 * 512;
        for (int i = tid; i < CH * PATCH * PATCH; i += 256) {
            int cc  = i / (PATCH * PATCH);
            int rem = i - cc * (PATCH * PATCH);
            int rr  = rem / PATCH;
            int c2  = rem - rr * PATCH;
            int r  = rbase + rr;
            int cl = cbase + c2;
            float v = 0.f;
            if ((unsigned)r < 512u && (unsigned)cl < 512u)
                v = xn[(size_t)cc * (512 * 512) + r * 512 + cl];
            x_s[cc][rr][c2] = v;
        }
        __syncthreads();

        // ---- compute y tile: y_s[cc][oh_l][ow_l], 512 values / 256 threads ----
        for (int q = tid; q < CH * 64; q += 256) {
            int cc = q >> 6;
            int p  = q & 63;
            int r0 = (p >> 3) * 2;
            int cl0 = (p & 7) * 2;
            float s = 0.f;
            #pragma unroll
            for (int a = 0; a < 4; a++)
                #pragma unroll
                for (int b = 0; b < 4; b++)
                    s += (kkn[a] * kkn[b]) * x_s[cc][r0 + a][cl0 + b];
            y_s[cc][p >> 3][p & 7] = s;
        }
        __syncthreads();

        // ---- register-blocked accumulate: 8 oc x 8 sp per thread ----
        #pragma unroll
        for (int cc = 0; cc < CH; cc++) {
            float4 ya = *(const float4*)&y_s[cc][sp_g][0];
            float4 yb = *(const float4*)&y_s[cc][sp_g][4];
            float4 wa = *(const float4*)&w_s[cc][oc_g * 8];
            float4 wb = *(const float4*)&w_s[cc][oc_g * 8 + 4];
            float yv[8] = {ya.x, ya.y, ya.z, ya.w, yb.x, yb.y, yb.z, yb.w};
            float wv[8] = {wa.x, wa.y, wa.z, wa.w, wb.x, wb.y, wb.z, wb.w};
            #pragma unroll
            for (int i = 0; i < 8; i++)
                #pragma unroll
                for (int j = 0; j < 8; j++)
                    acc[i][j] += wv[i] * yv[j];
        }
        __syncthreads();
    }

    // ---- epilogue: out[n, oc_g*8+i, oh0+sp_g, ow0 + 0..7] ----
    const size_t obase = (((size_t)n * 256 + (size_t)oc_g * 8) * 256
                          + (size_t)(oh0 + sp_g)) * 256 + ow0;
    #pragma unroll
    for (int i = 0; i < 8; i++) {
        float4 v0 = make_float4(acc[i][0], acc[i][1], acc[i][2], acc[i][3]);
        float4 v1 = make_float4(acc[i][4], acc[i][5], acc[i][6], acc[i][7]);
        *(float4*)&out[obase + (size_t)i * 65536]     = v0;
        *(float4*)&out[obase + (size_t)i * 65536 + 4] = v1;
    }
}

extern "C" void kernel_launch(void* const* d_in, const int* in_sizes, int n_in,
                              void* d_out, int out_size, void* d_ws, size_t ws_size,
                              hipStream_t stream) {
    const float* x = (const float*)d_in[0];
    const float* w = (const float*)d_in[1];
    float* out = (float*)d_out;

    dim3 grid(32, 32, 4);
    dim3 block(256);
    hipLaunchKernelGGL(fused_downconv, grid, block, 0, stream, x, w, out);
}